// Round 1
// baseline (1474.363 us; speedup 1.0000x reference)
//
#include <hip/hip_runtime.h>
#include <math.h>

// Problem constants (fixed by the reference)
#define TT 32
#define NN 20000
#define FF 128
#define HH 128
#define CC 10
#define RPB 32        // rows per block  (20000 / 32 = 625 blocks exactly)
#define NTHREADS 256

// LDS layout (floats): WihT[128][128] | WhhT[128][128] | xs[32][128] | hs[32][128]
// = 16384 + 16384 + 4096 + 4096 floats = 163840 bytes = full 160 KiB of a CDNA4 CU.

__global__ __launch_bounds__(NTHREADS, 1)
void grn_fused(const float* __restrict__ X,
               const float* __restrict__ W_ih,
               const float* __restrict__ W_hh,
               const float* __restrict__ b_ih,
               const float* __restrict__ b_hh,
               const float* __restrict__ gamma,
               const float* __restrict__ beta,
               const float* __restrict__ attn_w,
               const float* __restrict__ dense_W,
               const float* __restrict__ dense_b,
               float* __restrict__ out)
{
    __shared__ float smem[40960];
    float* WihT = smem;              // [k][h] = W_ih[h][k]
    float* WhhT = smem + 16384;      // [k][h] = W_hh[h][k]
    float* xs   = smem + 32768;      // [32][128]
    float* hs   = smem + 36864;      // [32][128]

    const int tid = threadIdx.x;
    const int n0  = blockIdx.x * RPB;

    // ---- stage both weight matrices transposed into LDS (one-time) ----
    for (int i = tid; i < HH * FF; i += NTHREADS) {
        const int h = i >> 7, f = i & 127;
        WihT[f * HH + h] = W_ih[i];
        WhhT[f * HH + h] = W_hh[i];
    }

    // matmul mapping: thread computes 4 h-outputs (h0..h0+3) for 4 rows
    const int hg = tid & 31;  const int h0 = hg * 4;
    const int rg = tid >> 5;                 // 0..7, rows rg*4 + r

    float4 bs;                                // b_ih + b_hh at h0..h0+3
    bs.x = b_ih[h0 + 0] + b_hh[h0 + 0];
    bs.y = b_ih[h0 + 1] + b_hh[h0 + 1];
    bs.z = b_ih[h0 + 2] + b_hh[h0 + 2];
    bs.w = b_ih[h0 + 3] + b_hh[h0 + 3];

    // LN mapping: 8 lanes per row, 16 columns each
    const int lrow = tid >> 3;   // 0..31
    const int l8   = tid & 7;    // cols l8*16 .. l8*16+15
    const int cbase = l8 * 16;

    // online-softmax state, replicated across the 8 lanes of a row group
    float st_m = -INFINITY, st_z = 0.f;
    float st_acc[CC];
#pragma unroll
    for (int c = 0; c < CC; ++c) st_acc[c] = 0.f;

    // ---- load x(t=0) tile: contiguous 4096 floats ----
    {
        const float4* src = (const float4*)(X + (size_t)n0 * FF);
        float4* dst = (float4*)xs;
#pragma unroll
        for (int i = 0; i < 4; ++i) dst[i * NTHREADS + tid] = src[i * NTHREADS + tid];
    }
    __syncthreads();

    // ---- init: h0 = X[0] @ W_ih.T + b_ih + b_hh  (no relu, not part of outs) ----
    {
        float acc[4][4];
#pragma unroll
        for (int r = 0; r < 4; ++r)
#pragma unroll
            for (int j = 0; j < 4; ++j) acc[r][j] = 0.f;

        for (int k4 = 0; k4 < 32; ++k4) {
            float4 xr[4];
#pragma unroll
            for (int r = 0; r < 4; ++r)
                xr[r] = *(const float4*)&xs[(rg * 4 + r) * HH + k4 * 4];
#pragma unroll
            for (int kk = 0; kk < 4; ++kk) {
                const float4 w1 = *(const float4*)&WihT[(k4 * 4 + kk) * HH + h0];
#pragma unroll
                for (int r = 0; r < 4; ++r) {
                    const float xv = ((const float*)&xr[r])[kk];
                    acc[r][0] += xv * w1.x;
                    acc[r][1] += xv * w1.y;
                    acc[r][2] += xv * w1.z;
                    acc[r][3] += xv * w1.w;
                }
            }
        }
#pragma unroll
        for (int r = 0; r < 4; ++r) {
            float4 o;
            o.x = acc[r][0] + bs.x;  o.y = acc[r][1] + bs.y;
            o.z = acc[r][2] + bs.z;  o.w = acc[r][3] + bs.w;
            *(float4*)&hs[(rg * 4 + r) * HH + h0] = o;
        }
    }
    __syncthreads();

    // ---- time loop ----
    for (int t = 0; t < TT; ++t) {
        // load x(t)  (prev matmul's xs reads are fenced by last iter's syncs)
        {
            const float4* src = (const float4*)(X + ((size_t)t * NN + n0) * FF);
            float4* dst = (float4*)xs;
#pragma unroll
            for (int i = 0; i < 4; ++i) dst[i * NTHREADS + tid] = src[i * NTHREADS + tid];
        }
        __syncthreads();

        // pre = xs @ WihT + hs @ WhhT   (K=128 each)
        float acc[4][4];
#pragma unroll
        for (int r = 0; r < 4; ++r)
#pragma unroll
            for (int j = 0; j < 4; ++j) acc[r][j] = 0.f;

        for (int k4 = 0; k4 < 32; ++k4) {
            float4 xr[4], hr[4];
#pragma unroll
            for (int r = 0; r < 4; ++r) {
                xr[r] = *(const float4*)&xs[(rg * 4 + r) * HH + k4 * 4];
                hr[r] = *(const float4*)&hs[(rg * 4 + r) * HH + k4 * 4];
            }
#pragma unroll
            for (int kk = 0; kk < 4; ++kk) {
                const float4 w1 = *(const float4*)&WihT[(k4 * 4 + kk) * HH + h0];
                const float4 w2 = *(const float4*)&WhhT[(k4 * 4 + kk) * HH + h0];
#pragma unroll
                for (int r = 0; r < 4; ++r) {
                    const float xv = ((const float*)&xr[r])[kk];
                    const float hv = ((const float*)&hr[r])[kk];
                    acc[r][0] += xv * w1.x;  acc[r][0] += hv * w2.x;
                    acc[r][1] += xv * w1.y;  acc[r][1] += hv * w2.y;
                    acc[r][2] += xv * w1.z;  acc[r][2] += hv * w2.z;
                    acc[r][3] += xv * w1.w;  acc[r][3] += hv * w2.w;
                }
            }
        }
        __syncthreads();   // all hs reads done before overwrite

        // h_new = relu(pre + bsum)  -> becomes next step's h state
#pragma unroll
        for (int r = 0; r < 4; ++r) {
            float4 o;
            o.x = fmaxf(acc[r][0] + bs.x, 0.f);
            o.y = fmaxf(acc[r][1] + bs.y, 0.f);
            o.z = fmaxf(acc[r][2] + bs.z, 0.f);
            o.w = fmaxf(acc[r][3] + bs.w, 0.f);
            *(float4*)&hs[(rg * 4 + r) * HH + h0] = o;
        }
        __syncthreads();   // hs ready for LN phase + next matmul

        // ---- LayerNorm + attn logit + dense, fused online over t ----
        {
            float v[16];
            float s1 = 0.f, s2 = 0.f;
            const float* hrow = &hs[lrow * HH + cbase];
#pragma unroll
            for (int q = 0; q < 4; ++q) {
                const float4 vv = *(const float4*)&hrow[q * 4];
                v[q*4+0] = vv.x; v[q*4+1] = vv.y; v[q*4+2] = vv.z; v[q*4+3] = vv.w;
                s1 += vv.x + vv.y + vv.z + vv.w;
                s2 += vv.x*vv.x + vv.y*vv.y + vv.z*vv.z + vv.w*vv.w;
            }
#pragma unroll
            for (int m = 1; m < 8; m <<= 1) {
                s1 += __shfl_xor(s1, m);
                s2 += __shfl_xor(s2, m);
            }
            const float mu  = s1 * (1.f / 128.f);
            const float var = s2 * (1.f / 128.f) - mu * mu;
            const float rs  = rsqrtf(var + 1e-5f);

            float y[16];
            float lsum = 0.f;
#pragma unroll
            for (int q = 0; q < 4; ++q) {
                const float4 g  = *(const float4*)&gamma[cbase + q * 4];
                const float4 b  = *(const float4*)&beta[cbase + q * 4];
                const float4 aw = *(const float4*)&attn_w[cbase + q * 4];
                float yy;
                yy = (v[q*4+0] - mu) * rs * g.x + b.x; y[q*4+0] = yy; lsum += yy * aw.x;
                yy = (v[q*4+1] - mu) * rs * g.y + b.y; y[q*4+1] = yy; lsum += yy * aw.y;
                yy = (v[q*4+2] - mu) * rs * g.z + b.z; y[q*4+2] = yy; lsum += yy * aw.z;
                yy = (v[q*4+3] - mu) * rs * g.w + b.w; y[q*4+3] = yy; lsum += yy * aw.w;
            }
            float dv[CC];
#pragma unroll
            for (int c = 0; c < CC; ++c) {
                float s = 0.f;
#pragma unroll
                for (int q = 0; q < 4; ++q) {
                    const float4 w = *(const float4*)&dense_W[c * HH + cbase + q * 4];
                    s += y[q*4+0]*w.x + y[q*4+1]*w.y + y[q*4+2]*w.z + y[q*4+3]*w.w;
                }
                dv[c] = s;
            }
            // reduce logit + dense vector across the 8 lanes of this row
#pragma unroll
            for (int m = 1; m < 8; m <<= 1) {
                lsum += __shfl_xor(lsum, m);
#pragma unroll
                for (int c = 0; c < CC; ++c) dv[c] += __shfl_xor(dv[c], m);
            }
            // online softmax over t (attn_b cancels by shift-invariance)
            const float mn = fmaxf(st_m, lsum);
            const float sc = __expf(st_m - mn);   // 0 on first step (st_m=-inf)
            const float e  = __expf(lsum - mn);
            st_z = st_z * sc + e;
#pragma unroll
            for (int c = 0; c < CC; ++c) st_acc[c] = st_acc[c] * sc + e * dv[c];
            st_m = mn;
        }
    }

    // ---- finalize: out[n][c] = acc[c]/Z + dense_b[c]  (Σa=1 folds dense_b out) ----
    {
        const int n = n0 + lrow;
        const float invz = 1.f / st_z;
#pragma unroll
        for (int c = 0; c < CC; ++c) {
            if ((c & 7) == l8)
                out[(size_t)n * CC + c] = st_acc[c] * invz + dense_b[c];
        }
    }
}

extern "C" void kernel_launch(void* const* d_in, const int* in_sizes, int n_in,
                              void* d_out, int out_size, void* d_ws, size_t ws_size,
                              hipStream_t stream) {
    const float* X      = (const float*)d_in[0];
    const float* W_ih   = (const float*)d_in[1];
    const float* W_hh   = (const float*)d_in[2];
    const float* b_ih   = (const float*)d_in[3];
    const float* b_hh   = (const float*)d_in[4];
    const float* gamma  = (const float*)d_in[5];
    const float* beta   = (const float*)d_in[6];
    const float* attn_w = (const float*)d_in[7];
    // d_in[8] = attn_b: cancels inside the softmax (shift invariance) — unused.
    const float* dW     = (const float*)d_in[9];
    const float* db     = (const float*)d_in[10];
    float* out = (float*)d_out;
    (void)in_sizes; (void)n_in; (void)out_size; (void)d_ws; (void)ws_size;

    grn_fused<<<dim3(NN / RPB), dim3(NTHREADS), 0, stream>>>(
        X, W_ih, W_hh, b_ih, b_hh, gamma, beta, attn_w, dW, db, out);
}

// Round 3
// 331.409 us; speedup vs baseline: 4.4488x; 4.4488x over previous
//
#include <hip/hip_runtime.h>
#include <math.h>

// Problem constants (fixed by the reference)
#define TT 32
#define NN 20000
#define FF 128
#define HH 128
#define CC 10
#define RPB 32          // rows per block (20000/32 = 625 blocks exactly)
#define NTHREADS 256    // 4 waves

typedef __attribute__((ext_vector_type(8))) _Float16 f16x8;  // 4 VGPRs
typedef __attribute__((ext_vector_type(4))) _Float16 f16x4;  // 2 VGPRs
typedef __attribute__((ext_vector_type(4))) float f32x4;     // MFMA acc

// LDS layout (bytes):
//   [0,16384)        A_hi plane: 32 rows x 256 k x f16, XOR-swizzled 16B chunks
//   [16384,32768)    A_lo plane: same layout
//   [32768,98816)    Ws: 32 k-groups x (128 cols x 16B + 16B pad)  (f16 single)
// k<128 = x / W_ih^T half, k>=128 = h / W_hh^T half.
#define PLANE_LO 16384
#define SMW_OFF  32768
#define WSTRIDE  2064            // 128*16 + 16 pad: shifts banks 4/word-group per kg
#define A_ADDR(row, chunk) (((row) << 9) + ((((chunk) ^ ((row) & 15))) << 4))

__device__ __forceinline__ void split8(float4 a, float4 b, f16x8* hi, f16x8* lo) {
    float v[8] = {a.x, a.y, a.z, a.w, b.x, b.y, b.z, b.w};
    f16x8 h, l;
#pragma unroll
    for (int j = 0; j < 8; ++j) {
        _Float16 hh = (_Float16)v[j];
        h[j] = hh;
        l[j] = (_Float16)(v[j] - (float)hh);
    }
    *hi = h; *lo = l;
}

__global__ __launch_bounds__(NTHREADS, 1)
void grn_mfma_f16(const float* __restrict__ X,
                  const float* __restrict__ W_ih,
                  const float* __restrict__ W_hh,
                  const float* __restrict__ b_ih,
                  const float* __restrict__ b_hh,
                  const float* __restrict__ gamma,
                  const float* __restrict__ beta,
                  const float* __restrict__ attn_w,
                  const float* __restrict__ dense_W,
                  const float* __restrict__ dense_b,
                  float* __restrict__ out)
{
    __shared__ __align__(16) char smem[98816];
    char* smA = smem;

    const int tid  = threadIdx.x;
    const int lane = tid & 63;
    const int wave = tid >> 6;
    const int n0   = blockIdx.x * RPB;

    // ---- one-time: fused weights Ws[k][c] = (k<128 ? W_ih[c][k] : W_hh[c][k-128]), f16
    for (int jj = tid; jj < 4096; jj += NTHREADS) {
        const int kg = jj >> 7;          // 0..31
        const int c  = jj & 127;
        const int k0 = kg << 3;
        const float* src = (k0 < 128) ? (W_ih + c * 128 + k0)
                                      : (W_hh + c * 128 + (k0 - 128));
        float4 w0 = *(const float4*)src;
        float4 w1 = *(const float4*)(src + 4);
        f16x8 w;
        w[0]=(_Float16)w0.x; w[1]=(_Float16)w0.y; w[2]=(_Float16)w0.z; w[3]=(_Float16)w0.w;
        w[4]=(_Float16)w1.x; w[5]=(_Float16)w1.y; w[6]=(_Float16)w1.z; w[7]=(_Float16)w1.w;
        *(f16x8*)(smem + SMW_OFF + kg * WSTRIDE + c * 16) = w;
    }

    // ---- dense+attn B fragments in registers: col = lane&15 (class; 10 = attn logit)
    f16x8 wd[4];
    {
        const int c = lane & 15;
#pragma unroll
        for (int ks = 0; ks < 4; ++ks) {
            f16x8 pk;
#pragma unroll
            for (int j = 0; j < 8; ++j) {
                const int k = ks * 32 + ((lane >> 4) << 3) + j;
                float v = 0.f;
                if (c < 10)       v = dense_W[c * 128 + k];
                else if (c == 10) v = attn_w[k];
                pk[j] = (_Float16)v;
            }
            wd[ks] = pk;
        }
    }

    // ---- bias float4 per nt (cols this lane owns in the SWAPPED output layout)
    f32x4 bias4[2];
#pragma unroll
    for (int nt = 0; nt < 2; ++nt) {
        const int c0 = (wave << 5) + (nt << 4) + ((lane >> 4) << 2);
        float4 bi = *(const float4*)(b_ih + c0);
        float4 bh = *(const float4*)(b_hh + c0);
        bias4[nt][0] = bi.x + bh.x; bias4[nt][1] = bi.y + bh.y;
        bias4[nt][2] = bi.z + bh.z; bias4[nt][3] = bi.w + bh.w;
    }

    // ---- LN mapping: 8 lanes per row, 16 cols each; gamma/beta in regs
    const int rs = tid >> 3;     // 0..31
    const int l8 = tid & 7;
    const int cb = l8 << 4;
    float g[16], bb[16];
#pragma unroll
    for (int q = 0; q < 4; ++q) {
        float4 gv = *(const float4*)(gamma + cb + q * 4);
        float4 bv = *(const float4*)(beta  + cb + q * 4);
        g[q*4+0]=gv.x; g[q*4+1]=gv.y; g[q*4+2]=gv.z; g[q*4+3]=gv.w;
        bb[q*4+0]=bv.x; bb[q*4+1]=bv.y; bb[q*4+2]=bv.z; bb[q*4+3]=bv.w;
    }

    // ---- x staging mapping
    const int xrow = tid >> 4;   // 0..15 (also handles xrow+16)
    const int xch  = tid & 15;

    // ---- stage x(0) hi/lo, zero h halves of both planes
    {
        const float* xs0 = X + (size_t)(n0 + xrow) * FF + (xch << 3);
        float4 p0 = *(const float4*)xs0;
        float4 p1 = *(const float4*)(xs0 + 4);
        float4 p2 = *(const float4*)(xs0 + 16 * FF);
        float4 p3 = *(const float4*)(xs0 + 16 * FF + 4);
        f16x8 hi, lo;
        split8(p0, p1, &hi, &lo);
        *(f16x8*)(smA + A_ADDR(xrow, xch)) = hi;
        *(f16x8*)(smA + PLANE_LO + A_ADDR(xrow, xch)) = lo;
        split8(p2, p3, &hi, &lo);
        *(f16x8*)(smA + A_ADDR(xrow + 16, xch)) = hi;
        *(f16x8*)(smA + PLANE_LO + A_ADDR(xrow + 16, xch)) = lo;
        f16x8 z;
#pragma unroll
        for (int j = 0; j < 8; ++j) z[j] = (_Float16)0.f;
        // swizzle is a bijection within the h half -> raw clear covers it exactly
        for (int i = tid; i < 1024; i += NTHREADS) {
            const int pl  = i >> 9;
            const int row = (i >> 4) & 31;
            const int ch  = 16 + (i & 15);
            *(f16x8*)(smA + pl * PLANE_LO + (row << 9) + (ch << 4)) = z;
        }
    }
    __syncthreads();

    // ---- init: h0 = X[0] @ W_ih^T + b (h halves zero -> full-K is fine; NO relu)
    {
        f32x4 acc[2][2];   // [nt][mt], SWAPPED layout: lane&15 = sample row, regs = 4 cols
#pragma unroll
        for (int nt = 0; nt < 2; ++nt)
#pragma unroll
            for (int mt = 0; mt < 2; ++mt) acc[nt][mt] = (f32x4){0.f,0.f,0.f,0.f};
#pragma unroll
        for (int ks = 0; ks < 8; ++ks) {
            const int kc = (ks << 2) + (lane >> 4);
            f16x8 a0h = *(const f16x8*)(smA + A_ADDR(lane & 15, kc));
            f16x8 a0l = *(const f16x8*)(smA + PLANE_LO + A_ADDR(lane & 15, kc));
            f16x8 a1h = *(const f16x8*)(smA + A_ADDR(16 + (lane & 15), kc));
            f16x8 a1l = *(const f16x8*)(smA + PLANE_LO + A_ADDR(16 + (lane & 15), kc));
            const char* bp = smem + SMW_OFF + kc * WSTRIDE + (((wave << 5) + (lane & 15)) << 4);
            f16x8 b0 = *(const f16x8*)bp;
            f16x8 b1 = *(const f16x8*)(bp + 256);
            acc[0][0] = __builtin_amdgcn_mfma_f32_16x16x32_f16(b0, a0h, acc[0][0], 0, 0, 0);
            acc[0][0] = __builtin_amdgcn_mfma_f32_16x16x32_f16(b0, a0l, acc[0][0], 0, 0, 0);
            acc[0][1] = __builtin_amdgcn_mfma_f32_16x16x32_f16(b0, a1h, acc[0][1], 0, 0, 0);
            acc[0][1] = __builtin_amdgcn_mfma_f32_16x16x32_f16(b0, a1l, acc[0][1], 0, 0, 0);
            acc[1][0] = __builtin_amdgcn_mfma_f32_16x16x32_f16(b1, a0h, acc[1][0], 0, 0, 0);
            acc[1][0] = __builtin_amdgcn_mfma_f32_16x16x32_f16(b1, a0l, acc[1][0], 0, 0, 0);
            acc[1][1] = __builtin_amdgcn_mfma_f32_16x16x32_f16(b1, a1h, acc[1][1], 0, 0, 0);
            acc[1][1] = __builtin_amdgcn_mfma_f32_16x16x32_f16(b1, a1l, acc[1][1], 0, 0, 0);
        }
        __syncthreads();
#pragma unroll
        for (int nt = 0; nt < 2; ++nt)
#pragma unroll
        for (int mt = 0; mt < 2; ++mt) {
            const int row = (lane & 15) + (mt << 4);
            const int c0  = (wave << 5) + (nt << 4) + ((lane >> 4) << 2);
            f16x4 hi4, lo4;
#pragma unroll
            for (int q = 0; q < 4; ++q) {
                const float v = acc[nt][mt][q] + bias4[nt][q];
                _Float16 hh = (_Float16)v;
                hi4[q] = hh;
                lo4[q] = (_Float16)(v - (float)hh);
            }
            const int kch  = 16 + (c0 >> 3);
            const int addr = (row << 9) + (((kch ^ (row & 15))) << 4) + ((c0 & 4) << 1);
            *(f16x4*)(smA + addr) = hi4;
            *(f16x4*)(smA + PLANE_LO + addr) = lo4;
        }
    }
    __syncthreads();

    // ---- online softmax state (slot s = (mt<<2)+r; class col = lane&15; replicated per wave)
    float stm[8], stz[8], sta[8];
#pragma unroll
    for (int s = 0; s < 8; ++s) { stm[s] = -INFINITY; stz[s] = 0.f; sta[s] = 0.f; }

    // ================= time loop =================
    for (int t = 0; t < TT; ++t) {
        // prefetch x(t+1) into registers (overlaps P2)
        float4 p0, p1, p2, p3;
        if (t < TT - 1) {
            const float* xs0 = X + ((size_t)(t + 1) * NN + n0 + xrow) * FF + (xch << 3);
            p0 = *(const float4*)xs0;
            p1 = *(const float4*)(xs0 + 4);
            p2 = *(const float4*)(xs0 + 16 * FF);
            p3 = *(const float4*)(xs0 + 16 * FF + 4);
        }

        // ---- P2: pre = [x|h] @ Ws, hi+lo chains (M=32, N=128 wave-split, K=256)
        f32x4 acc[2][2];
#pragma unroll
        for (int nt = 0; nt < 2; ++nt)
#pragma unroll
            for (int mt = 0; mt < 2; ++mt) acc[nt][mt] = (f32x4){0.f,0.f,0.f,0.f};
#pragma unroll
        for (int ks = 0; ks < 8; ++ks) {
            const int kc = (ks << 2) + (lane >> 4);
            f16x8 a0h = *(const f16x8*)(smA + A_ADDR(lane & 15, kc));
            f16x8 a0l = *(const f16x8*)(smA + PLANE_LO + A_ADDR(lane & 15, kc));
            f16x8 a1h = *(const f16x8*)(smA + A_ADDR(16 + (lane & 15), kc));
            f16x8 a1l = *(const f16x8*)(smA + PLANE_LO + A_ADDR(16 + (lane & 15), kc));
            const char* bp = smem + SMW_OFF + kc * WSTRIDE + (((wave << 5) + (lane & 15)) << 4);
            f16x8 b0 = *(const f16x8*)bp;
            f16x8 b1 = *(const f16x8*)(bp + 256);
            acc[0][0] = __builtin_amdgcn_mfma_f32_16x16x32_f16(b0, a0h, acc[0][0], 0, 0, 0);
            acc[0][0] = __builtin_amdgcn_mfma_f32_16x16x32_f16(b0, a0l, acc[0][0], 0, 0, 0);
            acc[0][1] = __builtin_amdgcn_mfma_f32_16x16x32_f16(b0, a1h, acc[0][1], 0, 0, 0);
            acc[0][1] = __builtin_amdgcn_mfma_f32_16x16x32_f16(b0, a1l, acc[0][1], 0, 0, 0);
            acc[1][0] = __builtin_amdgcn_mfma_f32_16x16x32_f16(b1, a0h, acc[1][0], 0, 0, 0);
            acc[1][0] = __builtin_amdgcn_mfma_f32_16x16x32_f16(b1, a0l, acc[1][0], 0, 0, 0);
            acc[1][1] = __builtin_amdgcn_mfma_f32_16x16x32_f16(b1, a1h, acc[1][1], 0, 0, 0);
            acc[1][1] = __builtin_amdgcn_mfma_f32_16x16x32_f16(b1, a1l, acc[1][1], 0, 0, 0);
        }
        __syncthreads();   // B3: x/h reads done

        // ---- P3: h_new = relu(pre + bias) -> h half, hi/lo, b64 writes (k-contiguous)
#pragma unroll
        for (int nt = 0; nt < 2; ++nt)
#pragma unroll
        for (int mt = 0; mt < 2; ++mt) {
            const int row = (lane & 15) + (mt << 4);
            const int c0  = (wave << 5) + (nt << 4) + ((lane >> 4) << 2);
            f16x4 hi4, lo4;
#pragma unroll
            for (int q = 0; q < 4; ++q) {
                const float v = fmaxf(acc[nt][mt][q] + bias4[nt][q], 0.f);
                _Float16 hh = (_Float16)v;
                hi4[q] = hh;
                lo4[q] = (_Float16)(v - (float)hh);
            }
            const int kch  = 16 + (c0 >> 3);
            const int addr = (row << 9) + (((kch ^ (row & 15))) << 4) + ((c0 & 4) << 1);
            *(f16x4*)(smA + addr) = hi4;
            *(f16x4*)(smA + PLANE_LO + addr) = lo4;
        }
        __syncthreads();   // B4: h_new visible

        // ---- P4: LayerNorm (reads h hi-plane) -> y f16 into x half of hi plane
        {
            f16x8 h0v = *(const f16x8*)(smA + A_ADDR(rs, 16 + (l8 << 1)));
            f16x8 h1v = *(const f16x8*)(smA + A_ADDR(rs, 16 + (l8 << 1) + 1));
            float v[16];
            float s1 = 0.f, s2 = 0.f;
#pragma unroll
            for (int j = 0; j < 8; ++j) { v[j] = (float)h0v[j]; v[8 + j] = (float)h1v[j]; }
#pragma unroll
            for (int j = 0; j < 16; ++j) { s1 += v[j]; s2 += v[j] * v[j]; }
            s1 += __shfl_xor(s1, 1); s2 += __shfl_xor(s2, 1);
            s1 += __shfl_xor(s1, 2); s2 += __shfl_xor(s2, 2);
            s1 += __shfl_xor(s1, 4); s2 += __shfl_xor(s2, 4);
            const float mu  = s1 * (1.f / 128.f);
            const float var = s2 * (1.f / 128.f) - mu * mu;
            const float rsi = rsqrtf(var + 1e-5f);
            f16x8 y0, y1;
#pragma unroll
            for (int j = 0; j < 8; ++j)
                y0[j] = (_Float16)((v[j] - mu) * rsi * g[j] + bb[j]);
#pragma unroll
            for (int j = 0; j < 8; ++j)
                y1[j] = (_Float16)((v[8 + j] - mu) * rsi * g[8 + j] + bb[8 + j]);
            *(f16x8*)(smA + A_ADDR(rs, (l8 << 1)))     = y0;
            *(f16x8*)(smA + A_ADDR(rs, (l8 << 1) + 1)) = y1;
        }
        __syncthreads();   // B5: y visible

        // ---- P5: [dense|logit] = y @ B2 (M=32, N=16, K=128; unswapped layout)
        f32x4 acc2[2];
        acc2[0] = (f32x4){0.f,0.f,0.f,0.f};
        acc2[1] = (f32x4){0.f,0.f,0.f,0.f};
#pragma unroll
        for (int ks = 0; ks < 4; ++ks) {
            const int kc = (ks << 2) + (lane >> 4);
            f16x8 a0 = *(const f16x8*)(smA + A_ADDR(lane & 15, kc));
            f16x8 a1 = *(const f16x8*)(smA + A_ADDR(16 + (lane & 15), kc));
            acc2[0] = __builtin_amdgcn_mfma_f32_16x16x32_f16(a0, wd[ks], acc2[0], 0, 0, 0);
            acc2[1] = __builtin_amdgcn_mfma_f32_16x16x32_f16(a1, wd[ks], acc2[1], 0, 0, 0);
        }

        // ---- online softmax over t (logit = class col 10 of each 16-lane group)
#pragma unroll
        for (int mt = 0; mt < 2; ++mt)
#pragma unroll
        for (int r = 0; r < 4; ++r) {
            const int s = (mt << 2) + r;
            const float dval = acc2[mt][r];
            const float lg = __shfl(dval, (lane & 48) + 10);
            const float mn = fmaxf(stm[s], lg);
            const float sc = __expf(stm[s] - mn);   // 0 on first step
            const float e  = __expf(lg - mn);
            stz[s] = stz[s] * sc + e;
            sta[s] = sta[s] * sc + e * dval;
            stm[s] = mn;
        }

        // ---- stage x(t+1) hi/lo (after all waves' y reads)
        if (t < TT - 1) {
            __syncthreads();   // B6: y reads done
            f16x8 hi, lo;
            split8(p0, p1, &hi, &lo);
            *(f16x8*)(smA + A_ADDR(xrow, xch)) = hi;
            *(f16x8*)(smA + PLANE_LO + A_ADDR(xrow, xch)) = lo;
            split8(p2, p3, &hi, &lo);
            *(f16x8*)(smA + A_ADDR(xrow + 16, xch)) = hi;
            *(f16x8*)(smA + PLANE_LO + A_ADDR(xrow + 16, xch)) = lo;
            __syncthreads();   // B7: x(t+1) visible
        }
    }

    // ---- epilogue: waves hold identical state -> wave 0 writes
    if (wave == 0) {
        const int c = lane & 15;
        if (c < CC) {
            const float db = dense_b[c];
#pragma unroll
            for (int mt = 0; mt < 2; ++mt)
#pragma unroll
            for (int r = 0; r < 4; ++r) {
                const int s = (mt << 2) + r;
                const int row = (mt << 4) + ((lane >> 4) << 2) + r;
                out[(size_t)(n0 + row) * CC + c] = sta[s] / stz[s] + db;
            }
        }
    }
}

extern "C" void kernel_launch(void* const* d_in, const int* in_sizes, int n_in,
                              void* d_out, int out_size, void* d_ws, size_t ws_size,
                              hipStream_t stream) {
    const float* X      = (const float*)d_in[0];
    const float* W_ih   = (const float*)d_in[1];
    const float* W_hh   = (const float*)d_in[2];
    const float* b_ih   = (const float*)d_in[3];
    const float* b_hh   = (const float*)d_in[4];
    const float* gamma  = (const float*)d_in[5];
    const float* beta   = (const float*)d_in[6];
    const float* attn_w = (const float*)d_in[7];
    // d_in[8] = attn_b: cancels in softmax (shift invariance) — unused.
    const float* dW     = (const float*)d_in[9];
    const float* db     = (const float*)d_in[10];
    float* out = (float*)d_out;
    (void)in_sizes; (void)n_in; (void)out_size; (void)d_ws; (void)ws_size;

    grn_mfma_f16<<<dim3(NN / RPB), dim3(NTHREADS), 0, stream>>>(
        X, W_ih, W_hh, b_ih, b_hh, gamma, beta, attn_w, dW, db, out);
}

// Round 4
// 217.769 us; speedup vs baseline: 6.7703x; 1.5218x over previous
//
#include <hip/hip_runtime.h>
#include <math.h>

// Problem constants (fixed by the reference)
#define TT 32
#define NN 20000
#define FF 128
#define HH 128
#define CC 10
#define RPB 32          // rows per block (20000/32 = 625 blocks exactly)
#define NTHREADS 512    // 8 waves -> 2 waves/SIMD

typedef __attribute__((ext_vector_type(8))) _Float16 f16x8;  // 4 VGPRs
typedef __attribute__((ext_vector_type(4))) _Float16 f16x4;  // 2 VGPRs
typedef __attribute__((ext_vector_type(4))) float f32x4;     // MFMA acc

// LDS layout (bytes):
//   [0,16384)        A_hi plane: 32 rows x 256 k x f16, XOR-swizzled 16B chunks
//   [16384,32768)    A_lo plane: same layout
//   [32768,98816)    Ws: 32 k-groups x (128 cols x 16B + 16B pad)  (f16 single)
//   [98816,107008)   y: 32 rows x 128 f16, XOR-swizzled 16B chunks
// A chunks 0-15 = x / W_ih^T half (k 0..127), 16-31 = h / W_hh^T half.
#define PLANE_LO 16384
#define SMW_OFF  32768
#define WSTRIDE  2064            // 128*16 + 16 pad: shifts banks per k-group
#define Y_OFF    98816
#define A_ADDR(row, chunk) (((row) << 9) + ((((chunk) ^ ((row) & 15))) << 4))
#define Y_ADDR(row, chunk) (Y_OFF + ((row) << 8) + ((((chunk) ^ ((row) & 15))) << 4))

__device__ __forceinline__ void split8(float4 a, float4 b, f16x8* hi, f16x8* lo) {
    float v[8] = {a.x, a.y, a.z, a.w, b.x, b.y, b.z, b.w};
    f16x8 h, l;
#pragma unroll
    for (int j = 0; j < 8; ++j) {
        _Float16 hh = (_Float16)v[j];
        h[j] = hh;
        l[j] = (_Float16)(v[j] - (float)hh);
    }
    *hi = h; *lo = l;
}

__global__ __launch_bounds__(NTHREADS, 1)
void grn8(const float* __restrict__ X,
          const float* __restrict__ W_ih,
          const float* __restrict__ W_hh,
          const float* __restrict__ b_ih,
          const float* __restrict__ b_hh,
          const float* __restrict__ gamma,
          const float* __restrict__ beta,
          const float* __restrict__ attn_w,
          const float* __restrict__ dense_W,
          const float* __restrict__ dense_b,
          float* __restrict__ out)
{
    __shared__ __align__(16) char smem[107008];
    char* smA = smem;

    const int tid  = threadIdx.x;
    const int lane = tid & 63;
    const int wave = tid >> 6;       // 0..7
    const int n0   = blockIdx.x * RPB;

    // ---- one-time: fused weights Ws[k][c] = (k<128 ? W_ih[c][k] : W_hh[c][k-128]), f16
    for (int jj = tid; jj < 4096; jj += NTHREADS) {
        const int kg = jj >> 7;          // 0..31
        const int c  = jj & 127;
        const int k0 = kg << 3;
        const float* src = (k0 < 128) ? (W_ih + c * 128 + k0)
                                      : (W_hh + c * 128 + (k0 - 128));
        float4 w0 = *(const float4*)src;
        float4 w1 = *(const float4*)(src + 4);
        f16x8 w;
        w[0]=(_Float16)w0.x; w[1]=(_Float16)w0.y; w[2]=(_Float16)w0.z; w[3]=(_Float16)w0.w;
        w[4]=(_Float16)w1.x; w[5]=(_Float16)w1.y; w[6]=(_Float16)w1.z; w[7]=(_Float16)w1.w;
        *(f16x8*)(smem + SMW_OFF + kg * WSTRIDE + c * 16) = w;
    }

    // ---- dense+attn B fragments in registers (used by waves 0,1; col 10 = attn logit)
    f16x8 wd[4];
    {
        const int c = lane & 15;
#pragma unroll
        for (int ks = 0; ks < 4; ++ks) {
            f16x8 pk;
#pragma unroll
            for (int j = 0; j < 8; ++j) {
                const int k = ks * 32 + ((lane >> 4) << 3) + j;
                float v = 0.f;
                if (c < 10)       v = dense_W[c * 128 + k];
                else if (c == 10) v = attn_w[k];
                pk[j] = (_Float16)v;
            }
            wd[ks] = pk;
        }
    }

    // ---- bias float4 (cols this lane owns in swapped layout; 16-col wave stripe)
    const int c0 = (wave << 4) + ((lane >> 4) << 2);
    f32x4 bias4;
    {
        float4 bi = *(const float4*)(b_ih + c0);
        float4 bh = *(const float4*)(b_hh + c0);
        bias4[0] = bi.x + bh.x; bias4[1] = bi.y + bh.y;
        bias4[2] = bi.z + bh.z; bias4[3] = bi.w + bh.w;
    }
    const int kch   = 16 + (c0 >> 3);            // h-half chunk for P3 writes
    const int c0off = (c0 & 4) << 1;             // byte offset within chunk

    // ---- LN mapping: 16 lanes per row, 8 cols each; gamma/beta in regs
    const int lrow = tid >> 4;   // 0..31
    const int lc   = tid & 15;   // chunk / col-group
    float g[8], bb[8];
    {
        const int cb = lc << 3;
        float4 g0 = *(const float4*)(gamma + cb);
        float4 g1 = *(const float4*)(gamma + cb + 4);
        float4 b0 = *(const float4*)(beta  + cb);
        float4 b1 = *(const float4*)(beta  + cb + 4);
        g[0]=g0.x; g[1]=g0.y; g[2]=g0.z; g[3]=g0.w;
        g[4]=g1.x; g[5]=g1.y; g[6]=g1.z; g[7]=g1.w;
        bb[0]=b0.x; bb[1]=b0.y; bb[2]=b0.z; bb[3]=b0.w;
        bb[4]=b1.x; bb[5]=b1.y; bb[6]=b1.z; bb[7]=b1.w;
    }

    // ---- stage x(0) hi/lo (one row-chunk per thread), zero h halves
    {
        const float* xs0 = X + (size_t)(n0 + lrow) * FF + (lc << 3);
        float4 p0 = *(const float4*)xs0;
        float4 p1 = *(const float4*)(xs0 + 4);
        f16x8 hi, lo;
        split8(p0, p1, &hi, &lo);
        *(f16x8*)(smA + A_ADDR(lrow, lc)) = hi;
        *(f16x8*)(smA + PLANE_LO + A_ADDR(lrow, lc)) = lo;
        f16x8 z;
#pragma unroll
        for (int j = 0; j < 8; ++j) z[j] = (_Float16)0.f;
        // swizzle is a bijection within the h half -> raw clear covers it exactly
        for (int i = tid; i < 1024; i += NTHREADS) {
            const int pl  = i >> 9;
            const int row = (i >> 4) & 31;
            const int ch  = 16 + (i & 15);
            *(f16x8*)(smA + pl * PLANE_LO + (row << 9) + (ch << 4)) = z;
        }
    }
    __syncthreads();

    // ---- init: h0 = X[0] @ W_ih^T + b (h halves zero -> full-K fine; NO relu)
    {
        f32x4 acc[2];   // [mt]; swapped layout: lane&15 = sample row, regs = 4 cols
        acc[0] = (f32x4){0.f,0.f,0.f,0.f};
        acc[1] = (f32x4){0.f,0.f,0.f,0.f};
#pragma unroll
        for (int ks = 0; ks < 8; ++ks) {
            const int kc = (ks << 2) + (lane >> 4);
            f16x8 a0h = *(const f16x8*)(smA + A_ADDR(lane & 15, kc));
            f16x8 a0l = *(const f16x8*)(smA + PLANE_LO + A_ADDR(lane & 15, kc));
            f16x8 a1h = *(const f16x8*)(smA + A_ADDR(16 + (lane & 15), kc));
            f16x8 a1l = *(const f16x8*)(smA + PLANE_LO + A_ADDR(16 + (lane & 15), kc));
            f16x8 b0 = *(const f16x8*)(smem + SMW_OFF + kc * WSTRIDE
                                       + (((wave << 4) + (lane & 15)) << 4));
            acc[0] = __builtin_amdgcn_mfma_f32_16x16x32_f16(b0, a0h, acc[0], 0, 0, 0);
            acc[0] = __builtin_amdgcn_mfma_f32_16x16x32_f16(b0, a0l, acc[0], 0, 0, 0);
            acc[1] = __builtin_amdgcn_mfma_f32_16x16x32_f16(b0, a1h, acc[1], 0, 0, 0);
            acc[1] = __builtin_amdgcn_mfma_f32_16x16x32_f16(b0, a1l, acc[1], 0, 0, 0);
        }
        __syncthreads();   // all reads of zero-h done before overwrite
#pragma unroll
        for (int mt = 0; mt < 2; ++mt) {
            const int row = (lane & 15) + (mt << 4);
            f16x4 hi4, lo4;
#pragma unroll
            for (int q = 0; q < 4; ++q) {
                const float v = acc[mt][q] + bias4[q];
                _Float16 hh = (_Float16)v;
                hi4[q] = hh;
                lo4[q] = (_Float16)(v - (float)hh);
            }
            const int addr = (row << 9) + (((kch ^ (row & 15))) << 4) + c0off;
            *(f16x4*)(smA + addr) = hi4;
            *(f16x4*)(smA + PLANE_LO + addr) = lo4;
        }
    }
    __syncthreads();

    // ---- online softmax state (waves 0,1: 4 row-slots each; class col = lane&15)
    float stm[4], stz[4], sta[4];
#pragma unroll
    for (int s = 0; s < 4; ++s) { stm[s] = -INFINITY; stz[s] = 0.f; sta[s] = 0.f; }

    // ================= time loop =================
    for (int t = 0; t < TT; ++t) {
        // prefetch x(t+1) (one row-chunk per thread; overlaps P2)
        float4 p0, p1;
        if (t < TT - 1) {
            const float* xs0 = X + ((size_t)(t + 1) * NN + n0 + lrow) * FF + (lc << 3);
            p0 = *(const float4*)xs0;
            p1 = *(const float4*)(xs0 + 4);
        }

        // ---- P2: pre = [x|h] @ Ws, hi+lo chains (M=32, N=16/wave, K=256)
        f32x4 acc[2];
        acc[0] = (f32x4){0.f,0.f,0.f,0.f};
        acc[1] = (f32x4){0.f,0.f,0.f,0.f};
#pragma unroll
        for (int ks = 0; ks < 8; ++ks) {
            const int kc = (ks << 2) + (lane >> 4);
            f16x8 a0h = *(const f16x8*)(smA + A_ADDR(lane & 15, kc));
            f16x8 a0l = *(const f16x8*)(smA + PLANE_LO + A_ADDR(lane & 15, kc));
            f16x8 a1h = *(const f16x8*)(smA + A_ADDR(16 + (lane & 15), kc));
            f16x8 a1l = *(const f16x8*)(smA + PLANE_LO + A_ADDR(16 + (lane & 15), kc));
            f16x8 b0 = *(const f16x8*)(smem + SMW_OFF + kc * WSTRIDE
                                       + (((wave << 4) + (lane & 15)) << 4));
            acc[0] = __builtin_amdgcn_mfma_f32_16x16x32_f16(b0, a0h, acc[0], 0, 0, 0);
            acc[0] = __builtin_amdgcn_mfma_f32_16x16x32_f16(b0, a0l, acc[0], 0, 0, 0);
            acc[1] = __builtin_amdgcn_mfma_f32_16x16x32_f16(b0, a1h, acc[1], 0, 0, 0);
            acc[1] = __builtin_amdgcn_mfma_f32_16x16x32_f16(b0, a1l, acc[1], 0, 0, 0);
        }
        __syncthreads();   // B3: all x/h reads done

        // ---- P3: h_new = relu(pre + bias) -> h half (hi/lo) + stage x(t+1) -> x half
#pragma unroll
        for (int mt = 0; mt < 2; ++mt) {
            const int row = (lane & 15) + (mt << 4);
            f16x4 hi4, lo4;
#pragma unroll
            for (int q = 0; q < 4; ++q) {
                const float v = fmaxf(acc[mt][q] + bias4[q], 0.f);
                _Float16 hh = (_Float16)v;
                hi4[q] = hh;
                lo4[q] = (_Float16)(v - (float)hh);
            }
            const int addr = (row << 9) + (((kch ^ (row & 15))) << 4) + c0off;
            *(f16x4*)(smA + addr) = hi4;
            *(f16x4*)(smA + PLANE_LO + addr) = lo4;
        }
        if (t < TT - 1) {
            f16x8 hi, lo;
            split8(p0, p1, &hi, &lo);
            *(f16x8*)(smA + A_ADDR(lrow, lc)) = hi;
            *(f16x8*)(smA + PLANE_LO + A_ADDR(lrow, lc)) = lo;
        }
        __syncthreads();   // B4: h_new + x(t+1) visible

        // ---- P4: LayerNorm (h hi-plane) -> y f16 into y buffer
        {
            f16x8 hv = *(const f16x8*)(smA + A_ADDR(lrow, 16 + lc));
            float v[8];
            float s1 = 0.f, s2 = 0.f;
#pragma unroll
            for (int j = 0; j < 8; ++j) { v[j] = (float)hv[j]; }
#pragma unroll
            for (int j = 0; j < 8; ++j) { s1 += v[j]; s2 += v[j] * v[j]; }
            s1 += __shfl_xor(s1, 1); s2 += __shfl_xor(s2, 1);
            s1 += __shfl_xor(s1, 2); s2 += __shfl_xor(s2, 2);
            s1 += __shfl_xor(s1, 4); s2 += __shfl_xor(s2, 4);
            s1 += __shfl_xor(s1, 8); s2 += __shfl_xor(s2, 8);
            const float mu  = s1 * (1.f / 128.f);
            const float var = s2 * (1.f / 128.f) - mu * mu;
            const float rsi = rsqrtf(var + 1e-5f);
            f16x8 y;
#pragma unroll
            for (int j = 0; j < 8; ++j)
                y[j] = (_Float16)((v[j] - mu) * rsi * g[j] + bb[j]);
            *(f16x8*)(smem + Y_ADDR(lrow, lc)) = y;
        }
        __syncthreads();   // B5: y visible

        // ---- P5 (waves 0,1 only): [dense|logit] = y @ B2 (M=16/wave, K=128) + softmax
        if (wave < 2) {
            f32x4 acc2 = (f32x4){0.f,0.f,0.f,0.f};
#pragma unroll
            for (int ks = 0; ks < 4; ++ks) {
                const int kc = (ks << 2) + (lane >> 4);
                f16x8 a = *(const f16x8*)(smem + Y_ADDR((wave << 4) + (lane & 15), kc));
                acc2 = __builtin_amdgcn_mfma_f32_16x16x32_f16(a, wd[ks], acc2, 0, 0, 0);
            }
#pragma unroll
            for (int r = 0; r < 4; ++r) {
                const float dval = acc2[r];
                const float lg = __shfl(dval, (lane & 48) + 10);
                const float mn = fmaxf(stm[r], lg);
                const float sc = __expf(stm[r] - mn);   // 0 on first step
                const float e  = __expf(lg - mn);
                stz[r] = stz[r] * sc + e;
                sta[r] = sta[r] * sc + e * dval;
                stm[r] = mn;
            }
        }
        // next iteration's B3 orders P5's y reads against P4(t+1)'s y writes
    }

    // ---- epilogue: wave w (0,1) owns rows w*16..w*16+15
    if (wave < 2) {
        const int c = lane & 15;
        if (c < CC) {
            const float db = dense_b[c];
#pragma unroll
            for (int r = 0; r < 4; ++r) {
                const int row = (wave << 4) + ((lane >> 4) << 2) + r;
                out[(size_t)(n0 + row) * CC + c] = sta[r] / stz[r] + db;
            }
        }
    }
}

extern "C" void kernel_launch(void* const* d_in, const int* in_sizes, int n_in,
                              void* d_out, int out_size, void* d_ws, size_t ws_size,
                              hipStream_t stream) {
    const float* X      = (const float*)d_in[0];
    const float* W_ih   = (const float*)d_in[1];
    const float* W_hh   = (const float*)d_in[2];
    const float* b_ih   = (const float*)d_in[3];
    const float* b_hh   = (const float*)d_in[4];
    const float* gamma  = (const float*)d_in[5];
    const float* beta   = (const float*)d_in[6];
    const float* attn_w = (const float*)d_in[7];
    // d_in[8] = attn_b: cancels in softmax (shift invariance) — unused.
    const float* dW     = (const float*)d_in[9];
    const float* db     = (const float*)d_in[10];
    float* out = (float*)d_out;
    (void)in_sizes; (void)n_in; (void)out_size; (void)d_ws; (void)ws_size;

    grn8<<<dim3(NN / RPB), dim3(NTHREADS), 0, stream>>>(
        X, W_ih, W_hh, b_ih, b_hh, gamma, beta, attn_w, dW, db, out);
}

// Round 8
// 200.500 us; speedup vs baseline: 7.3534x; 1.0861x over previous
//
#include <hip/hip_runtime.h>
#include <math.h>

// Problem constants (fixed by the reference)
#define TT 32
#define NN 20000
#define FF 128
#define HH 128
#define CC 10
#define RPB 32          // rows per block (20000/32 = 625 blocks exactly)
#define NTHREADS 512    // 8 waves (round-4 geometry)

typedef __attribute__((ext_vector_type(8))) _Float16 f16x8;  // 4 VGPRs
typedef __attribute__((ext_vector_type(4))) _Float16 f16x4;  // 2 VGPRs
typedef __attribute__((ext_vector_type(4))) float f32x4;     // MFMA acc

// d_ws layout (f16 elements):
//   [0, 32768)       Wsg[kg][c][j]: (f16)(k<128 ? W_ih[c][k] : W_hh[c][k-128]),
//                    k = kg*8+j; kg 0..31, c 0..127, j 0..7  (65536 B)
//   [32768, 34816)   WDg[kg][cc][j]: cc<10 dense_W[cc][k]; cc==10 attn_w[k]; else 0
//                    kg 0..15, cc 0..15, j 0..7               (4096 B)
//
// LDS layout (bytes), 40960 total:
//   [0,16384)      A_hi: 32 rows x 256 k x f16, XOR-swizzled 16B chunks
//                  (chunks 0-15 = x half, 16-31 = h half)
//   [16384,32768)  A_lo: same layout (error-compensation plane)
//   [32768,40960)  y: LN output, 32 rows x 128 f16, swizzled
#define PLANE_LO 16384
#define Y_OFF    32768
#define A_ADDR(row, chunk) (((row) << 9) + ((((chunk) ^ ((row) & 15))) << 4))
#define Y_ADDR(row, chunk) (Y_OFF + ((row) << 8) + ((((chunk) ^ ((row) & 15))) << 4))

__device__ __forceinline__ void split8(float4 a, float4 b, f16x8* hi, f16x8* lo) {
    float v[8] = {a.x, a.y, a.z, a.w, b.x, b.y, b.z, b.w};
    f16x8 h, l;
#pragma unroll
    for (int j = 0; j < 8; ++j) {
        _Float16 hh = (_Float16)v[j];
        h[j] = hh;
        l[j] = (_Float16)(v[j] - (float)hh);
    }
    *hi = h; *lo = l;
}

// ---- prep: convert weights to fragment-layout f16 in global scratch ----
__global__ __launch_bounds__(256, 1)
void grn_prep(const float* __restrict__ W_ih,
              const float* __restrict__ W_hh,
              const float* __restrict__ dense_W,
              const float* __restrict__ attn_w,
              _Float16* __restrict__ wsg)
{
    const int i  = blockIdx.x * 256 + threadIdx.x;   // 0..4095
    const int kg = i & 31;
    const int c  = i >> 5;
    const int k0 = kg << 3;
    const float* src = (k0 < 128) ? (W_ih + c * 128 + k0)
                                  : (W_hh + c * 128 + (k0 - 128));
    float4 w0 = *(const float4*)src;
    float4 w1 = *(const float4*)(src + 4);
    f16x8 w;
    w[0]=(_Float16)w0.x; w[1]=(_Float16)w0.y; w[2]=(_Float16)w0.z; w[3]=(_Float16)w0.w;
    w[4]=(_Float16)w1.x; w[5]=(_Float16)w1.y; w[6]=(_Float16)w1.z; w[7]=(_Float16)w1.w;
    *(f16x8*)(wsg + kg * 1024 + c * 8) = w;

    if (i < 256) {
        const int kg2 = i >> 4;          // 0..15
        const int cc  = i & 15;          // 0..15
        f16x8 d;
#pragma unroll
        for (int j = 0; j < 8; ++j) {
            const int k = (kg2 << 3) + j;
            float v = 0.f;
            if (cc < 10)       v = dense_W[cc * 128 + k];
            else if (cc == 10) v = attn_w[k];
            d[j] = (_Float16)v;
        }
        *(f16x8*)(wsg + 32768 + kg2 * 128 + cc * 8) = d;
    }
}

__global__ __launch_bounds__(NTHREADS, 1)
void grn_r8(const float* __restrict__ X,
            const _Float16* __restrict__ wsg,
            const float* __restrict__ b_ih,
            const float* __restrict__ b_hh,
            const float* __restrict__ gamma,
            const float* __restrict__ beta,
            const float* __restrict__ dense_b,
            float* __restrict__ out)
{
    __shared__ __align__(16) char smem[40960];
    char* smA = smem;

    const int tid  = threadIdx.x;
    const int lane = tid & 63;
    const int wave = tid >> 6;       // 0..7; wave owns cols wave*16..wave*16+15
    const int n0   = blockIdx.x * RPB;

    // ---- W stripe into registers via RAW 16B vector loads (no in-kernel convert):
    // Wf[ks] bits == round-4's LDS b0 bits for the same (wave, lane, ks).
    f16x8 Wf[8];
    {
        const int c = (wave << 4) + (lane & 15);
#pragma unroll
        for (int ks = 0; ks < 8; ++ks) {
            const int kc = (ks << 2) + (lane >> 4);
            Wf[ks] = *(const f16x8*)(wsg + kc * 1024 + c * 8);
        }
    }

    // ---- dense+attn fragments, raw loads (used by waves 0,1)
    f16x8 wd[4];
    {
        const int cc = lane & 15;
#pragma unroll
        for (int ks = 0; ks < 4; ++ks) {
            const int kc = (ks << 2) + (lane >> 4);
            wd[ks] = *(const f16x8*)(wsg + 32768 + kc * 128 + cc * 8);
        }
    }

    // ---- bias float4 (cols this lane owns in swapped layout; 16-col wave stripe)
    const int c0 = (wave << 4) + ((lane >> 4) << 2);
    f32x4 bias4;
    {
        float4 bi = *(const float4*)(b_ih + c0);
        float4 bh = *(const float4*)(b_hh + c0);
        bias4[0] = bi.x + bh.x; bias4[1] = bi.y + bh.y;
        bias4[2] = bi.z + bh.z; bias4[3] = bi.w + bh.w;
    }
    const int kch   = 16 + (c0 >> 3);            // h-half chunk for P3 writes
    const int c0off = (c0 & 4) << 1;             // byte offset within chunk

    // ---- LN mapping: 16 lanes per row, 8 cols each; gamma/beta in regs
    const int lrow = tid >> 4;   // 0..31
    const int lc   = tid & 15;   // chunk / col-group
    float g[8], bb[8];
    {
        const int cb = lc << 3;
        float4 g0 = *(const float4*)(gamma + cb);
        float4 g1 = *(const float4*)(gamma + cb + 4);
        float4 b0 = *(const float4*)(beta  + cb);
        float4 b1 = *(const float4*)(beta  + cb + 4);
        g[0]=g0.x; g[1]=g0.y; g[2]=g0.z; g[3]=g0.w;
        g[4]=g1.x; g[5]=g1.y; g[6]=g1.z; g[7]=g1.w;
        bb[0]=b0.x; bb[1]=b0.y; bb[2]=b0.z; bb[3]=b0.w;
        bb[4]=b1.x; bb[5]=b1.y; bb[6]=b1.z; bb[7]=b1.w;
    }

    // ---- stage x(0) hi/lo (one row-chunk per thread), zero h halves
    {
        const float* xs0 = X + (size_t)(n0 + lrow) * FF + (lc << 3);
        float4 p0 = *(const float4*)xs0;
        float4 p1 = *(const float4*)(xs0 + 4);
        f16x8 hi, lo;
        split8(p0, p1, &hi, &lo);
        *(f16x8*)(smA + A_ADDR(lrow, lc)) = hi;
        *(f16x8*)(smA + PLANE_LO + A_ADDR(lrow, lc)) = lo;
        f16x8 z;
#pragma unroll
        for (int j = 0; j < 8; ++j) z[j] = (_Float16)0.f;
        // swizzle is a bijection within the h half -> raw clear covers it exactly
        for (int i = tid; i < 1024; i += NTHREADS) {
            const int pl  = i >> 9;
            const int row = (i >> 4) & 31;
            const int ch  = 16 + (i & 15);
            *(f16x8*)(smA + pl * PLANE_LO + (row << 9) + (ch << 4)) = z;
        }
    }
    __syncthreads();

    // ---- init: h0 = X[0] @ W_ih^T + b (h halves zero -> full-K fine; NO relu)
    {
        f32x4 acc[2];   // [mt]; swapped layout: lane&15 = sample row, regs = 4 cols
        acc[0] = (f32x4){0.f,0.f,0.f,0.f};
        acc[1] = (f32x4){0.f,0.f,0.f,0.f};
#pragma unroll
        for (int ks = 0; ks < 8; ++ks) {
            const int kc = (ks << 2) + (lane >> 4);
            f16x8 a0h = *(const f16x8*)(smA + A_ADDR(lane & 15, kc));
            f16x8 a0l = *(const f16x8*)(smA + PLANE_LO + A_ADDR(lane & 15, kc));
            f16x8 a1h = *(const f16x8*)(smA + A_ADDR(16 + (lane & 15), kc));
            f16x8 a1l = *(const f16x8*)(smA + PLANE_LO + A_ADDR(16 + (lane & 15), kc));
            acc[0] = __builtin_amdgcn_mfma_f32_16x16x32_f16(Wf[ks], a0h, acc[0], 0, 0, 0);
            acc[0] = __builtin_amdgcn_mfma_f32_16x16x32_f16(Wf[ks], a0l, acc[0], 0, 0, 0);
            acc[1] = __builtin_amdgcn_mfma_f32_16x16x32_f16(Wf[ks], a1h, acc[1], 0, 0, 0);
            acc[1] = __builtin_amdgcn_mfma_f32_16x16x32_f16(Wf[ks], a1l, acc[1], 0, 0, 0);
        }
        __syncthreads();   // all reads of zero-h done before overwrite
#pragma unroll
        for (int mt = 0; mt < 2; ++mt) {
            const int row = (lane & 15) + (mt << 4);
            f16x4 hi4, lo4;
#pragma unroll
            for (int q = 0; q < 4; ++q) {
                const float v = acc[mt][q] + bias4[q];
                _Float16 hh = (_Float16)v;
                hi4[q] = hh;
                lo4[q] = (_Float16)(v - (float)hh);
            }
            const int addr = (row << 9) + (((kch ^ (row & 15))) << 4) + c0off;
            *(f16x4*)(smA + addr) = hi4;
            *(f16x4*)(smA + PLANE_LO + addr) = lo4;
        }
    }
    __syncthreads();

    // ---- online softmax state (waves 0,1: 4 row-slots each; class col = lane&15)
    float stm[4], stz[4], sta[4];
#pragma unroll
    for (int s = 0; s < 4; ++s) { stm[s] = -INFINITY; stz[s] = 0.f; sta[s] = 0.f; }

    // ================= time loop (round-4 order: P2;B;P3;B;P4;B;P5) =================
    for (int t = 0; t < TT; ++t) {
        // prefetch x(t+1) (one row-chunk per thread; overlaps P2)
        float4 p0, p1;
        if (t < TT - 1) {
            const float* xs0 = X + ((size_t)(t + 1) * NN + n0 + lrow) * FF + (lc << 3);
            p0 = *(const float4*)xs0;
            p1 = *(const float4*)(xs0 + 4);
        }

        // ---- P2: pre = [x|h] @ Ws, hi+lo chains (M=32, N=16/wave, K=256)
        f32x4 acc[2];
        acc[0] = (f32x4){0.f,0.f,0.f,0.f};
        acc[1] = (f32x4){0.f,0.f,0.f,0.f};
#pragma unroll
        for (int ks = 0; ks < 8; ++ks) {
            const int kc = (ks << 2) + (lane >> 4);
            f16x8 a0h = *(const f16x8*)(smA + A_ADDR(lane & 15, kc));
            f16x8 a0l = *(const f16x8*)(smA + PLANE_LO + A_ADDR(lane & 15, kc));
            f16x8 a1h = *(const f16x8*)(smA + A_ADDR(16 + (lane & 15), kc));
            f16x8 a1l = *(const f16x8*)(smA + PLANE_LO + A_ADDR(16 + (lane & 15), kc));
            acc[0] = __builtin_amdgcn_mfma_f32_16x16x32_f16(Wf[ks], a0h, acc[0], 0, 0, 0);
            acc[0] = __builtin_amdgcn_mfma_f32_16x16x32_f16(Wf[ks], a0l, acc[0], 0, 0, 0);
            acc[1] = __builtin_amdgcn_mfma_f32_16x16x32_f16(Wf[ks], a1h, acc[1], 0, 0, 0);
            acc[1] = __builtin_amdgcn_mfma_f32_16x16x32_f16(Wf[ks], a1l, acc[1], 0, 0, 0);
        }
        __syncthreads();   // B3: all x/h reads done

        // ---- P3: h_new = relu(pre + bias) -> h half (hi/lo) + stage x(t+1) -> x half
#pragma unroll
        for (int mt = 0; mt < 2; ++mt) {
            const int row = (lane & 15) + (mt << 4);
            f16x4 hi4, lo4;
#pragma unroll
            for (int q = 0; q < 4; ++q) {
                const float v = fmaxf(acc[mt][q] + bias4[q], 0.f);
                _Float16 hh = (_Float16)v;
                hi4[q] = hh;
                lo4[q] = (_Float16)(v - (float)hh);
            }
            const int addr = (row << 9) + (((kch ^ (row & 15))) << 4) + c0off;
            *(f16x4*)(smA + addr) = hi4;
            *(f16x4*)(smA + PLANE_LO + addr) = lo4;
        }
        if (t < TT - 1) {
            f16x8 hi, lo;
            split8(p0, p1, &hi, &lo);
            *(f16x8*)(smA + A_ADDR(lrow, lc)) = hi;
            *(f16x8*)(smA + PLANE_LO + A_ADDR(lrow, lc)) = lo;
        }
        __syncthreads();   // B4: h_new + x(t+1) visible

        // ---- P4: LayerNorm (h hi-plane) -> y f16 into y buffer
        {
            f16x8 hv = *(const f16x8*)(smA + A_ADDR(lrow, 16 + lc));
            float v[8];
            float s1 = 0.f, s2 = 0.f;
#pragma unroll
            for (int j = 0; j < 8; ++j) { v[j] = (float)hv[j]; }
#pragma unroll
            for (int j = 0; j < 8; ++j) { s1 += v[j]; s2 += v[j] * v[j]; }
            s1 += __shfl_xor(s1, 1); s2 += __shfl_xor(s2, 1);
            s1 += __shfl_xor(s1, 2); s2 += __shfl_xor(s2, 2);
            s1 += __shfl_xor(s1, 4); s2 += __shfl_xor(s2, 4);
            s1 += __shfl_xor(s1, 8); s2 += __shfl_xor(s2, 8);
            const float mu  = s1 * (1.f / 128.f);
            const float var = s2 * (1.f / 128.f) - mu * mu;
            const float rsi = rsqrtf(var + 1e-5f);
            f16x8 y;
#pragma unroll
            for (int j = 0; j < 8; ++j)
                y[j] = (_Float16)((v[j] - mu) * rsi * g[j] + bb[j]);
            *(f16x8*)(smem + Y_ADDR(lrow, lc)) = y;
        }
        __syncthreads();   // B5: y visible

        // ---- P5 (waves 0,1 only): [dense|logit] = y @ B2 (M=16/wave, K=128) + softmax
        if (wave < 2) {
            f32x4 acc2 = (f32x4){0.f,0.f,0.f,0.f};
#pragma unroll
            for (int ks = 0; ks < 4; ++ks) {
                const int kc = (ks << 2) + (lane >> 4);
                f16x8 a = *(const f16x8*)(smem + Y_ADDR((wave << 4) + (lane & 15), kc));
                acc2 = __builtin_amdgcn_mfma_f32_16x16x32_f16(a, wd[ks], acc2, 0, 0, 0);
            }
#pragma unroll
            for (int r = 0; r < 4; ++r) {
                const float dval = acc2[r];
                const float lg = __shfl(dval, (lane & 48) + 10);
                const float mn = fmaxf(stm[r], lg);
                const float sc = __expf(stm[r] - mn);   // 0 on first step
                const float e  = __expf(lg - mn);
                stz[r] = stz[r] * sc + e;
                sta[r] = sta[r] * sc + e * dval;
                stm[r] = mn;
            }
        }
        // next iteration's B3 orders P5's y reads against P4(t+1)'s y writes
    }

    // ---- epilogue: wave w (0,1) owns rows w*16..w*16+15
    if (wave < 2) {
        const int c = lane & 15;
        if (c < CC) {
            const float db = dense_b[c];
#pragma unroll
            for (int r = 0; r < 4; ++r) {
                const int row = (wave << 4) + ((lane >> 4) << 2) + r;
                out[(size_t)(n0 + row) * CC + c] = sta[r] / stz[r] + db;
            }
        }
    }
}

extern "C" void kernel_launch(void* const* d_in, const int* in_sizes, int n_in,
                              void* d_out, int out_size, void* d_ws, size_t ws_size,
                              hipStream_t stream) {
    const float* X      = (const float*)d_in[0];
    const float* W_ih   = (const float*)d_in[1];
    const float* W_hh   = (const float*)d_in[2];
    const float* b_ih   = (const float*)d_in[3];
    const float* b_hh   = (const float*)d_in[4];
    const float* gamma  = (const float*)d_in[5];
    const float* beta   = (const float*)d_in[6];
    const float* attn_w = (const float*)d_in[7];
    // d_in[8] = attn_b: cancels in softmax (shift invariance) — unused.
    const float* dW     = (const float*)d_in[9];
    const float* db     = (const float*)d_in[10];
    float* out = (float*)d_out;
    _Float16* wsg = (_Float16*)d_ws;
    (void)in_sizes; (void)n_in; (void)out_size; (void)ws_size;

    grn_prep<<<dim3(16), dim3(256), 0, stream>>>(W_ih, W_hh, dW, attn_w, wsg);
    grn_r8<<<dim3(NN / RPB), dim3(NTHREADS), 0, stream>>>(
        X, wsg, b_ih, b_hh, gamma, beta, db, out);
}